// Round 3
// baseline (433.168 us; speedup 1.0000x reference)
//
#include <hip/hip_runtime.h>
#include <hip/hip_bf16.h>
#include <math.h>
#include <stdint.h>

// ---------------------------------------------------------------------------
// attention_net (MI355X gfx950)
//   conv1: 2048->128 14x14 s1p1 | conv2: 128->128 ->7x7 s2p1 | conv3: ->4x4
//   All three convs: split-bf16 (hi+lo) MFMA 32x32x16, NHWC padded-16x16 A.
//   Then 1x1 heads -> scores(8,1614) -> greedy-NMS top6 -> bilinear crop.
// R3: 6 dispatches (was 11): unified prep, conv+reduce fused via atomic
//     counter (last-block reduces), heads+NMS fused, flat crop.
//     conv1 K-stage 64 (6 iters, halves per-iter barrier stalls), XOR-chunk
//     swizzled 64KB LDS, R0-style reg->LDS staging (proven fastest).
// Output floats: part_imgs[7225344], coords[192], top_prob[48], top_idx[48]
// ---------------------------------------------------------------------------

#define OFF_COORDS 7225344
#define OFF_PROB   7225536
#define OFF_IDX    7225584
#define NA 1614
#define K1TOT 18432

typedef __attribute__((ext_vector_type(8)))  short  short8;
typedef __attribute__((ext_vector_type(16))) float  floatx16;

__device__ inline void split_bf16(float v, unsigned short& h, unsigned short& l)
{
    __hip_bfloat16 hb = __float2bfloat16(v);
    float hv = __bfloat162float(hb);
    __hip_bfloat16 lb = __float2bfloat16(v - hv);
    h = *reinterpret_cast<unsigned short*>(&hb);
    l = *reinterpret_cast<unsigned short*>(&lb);
}

// ---- unified prep: 3713 blocks ---------------------------------------------
//  [0,1024)      prep_a : rpn NCHW fp32 -> padded NHWC split-bf16
//  [1024,2048)   prep_b1: wd1 -> b1 [co][tap*2048+ci] split-bf16 (LDS transpose)
//  [2048,3200)   prep_w23: wd2/wd3 -> b2/b3 [co][tap*128+ci]
//  [3200,3712)   zero d1ph/d1pl/d2ph/d2pl (pads must be 0 for fused reduce)
//  3712          zero counters
__global__ __launch_bounds__(256) void k_prep(const float* __restrict__ rpn,
                                              const float* __restrict__ w1,
                                              const float* __restrict__ w2,
                                              const float* __restrict__ w3,
                                              unsigned short* __restrict__ ah,
                                              unsigned short* __restrict__ al,
                                              unsigned short* __restrict__ b1h,
                                              unsigned short* __restrict__ b1l,
                                              unsigned short* __restrict__ b2h,
                                              unsigned short* __restrict__ b2l,
                                              unsigned short* __restrict__ b3h,
                                              unsigned short* __restrict__ b3l,
                                              short* __restrict__ z0,
                                              short* __restrict__ z1,
                                              short* __restrict__ z2,
                                              short* __restrict__ z3,
                                              int* __restrict__ cnt)
{
    __shared__ float tileA[64][65];
    __shared__ float tileB[9][260];
    const int bid = blockIdx.x;
    const int t   = threadIdx.x;

    if (bid < 1024) {                     // ---- prep_a
        const int cib  = (bid & 31) * 64;
        const int posb = ((bid >> 5) & 3) * 64;
        const int b    = bid >> 7;
#pragma unroll
        for (int it = 0; it < 16; ++it) {
            int idx  = it * 256 + t;
            int cil  = idx >> 6;
            int posl = idx & 63;
            int pos  = posb + posl;
            int py = pos >> 4, px = pos & 15;
            int y = py - 1, x = px - 1;
            float v = 0.0f;
            if ((unsigned)y < 14u && (unsigned)x < 14u)
                v = rpn[((size_t)(b * 2048 + cib + cil) * 14 + y) * 14 + x];
            tileA[cil][posl] = v;
        }
        __syncthreads();
#pragma unroll
        for (int it = 0; it < 16; ++it) {
            int idx  = it * 256 + t;
            int posl = idx >> 6;
            int cil  = idx & 63;
            float v = tileA[cil][posl];
            unsigned short h, l;
            split_bf16(v, h, l);
            size_t o = (size_t)(b * 256 + posb + posl) * 2048 + cib + cil;
            ah[o] = h; al[o] = l;
        }
    } else if (bid < 2048) {              // ---- prep_b (conv1)
        const int lb  = bid - 1024;
        const int ci0 = (lb & 7) * 256;
        const int co  = lb >> 3;
        const float* wc = w1 + (size_t)co * K1TOT + (size_t)ci0 * 9;
#pragma unroll
        for (int it = 0; it < 9; ++it) {
            int i = it * 256 + t;
            float v = wc[i];
            tileB[i % 9][i / 9] = v;
        }
        __syncthreads();
#pragma unroll
        for (int tap = 0; tap < 9; ++tap) {
            float v = tileB[tap][t];
            unsigned short h, l;
            split_bf16(v, h, l);
            size_t o = (size_t)co * K1TOT + (size_t)tap * 2048 + ci0 + t;
            b1h[o] = h; b1l[o] = l;
        }
    } else if (bid < 3200) {              // ---- prep_w23
        const int lb  = bid - 2048;
        const int tap = lb % 9;
        const int co  = lb / 9;
        const int z   = t >> 7;
        const int ci  = t & 127;
        const float* w = z ? w3 : w2;
        unsigned short* bh = z ? b3h : b2h;
        unsigned short* bl = z ? b3l : b2l;
        float v = w[((size_t)co * 128 + ci) * 9 + tap];
        unsigned short h, l;
        split_bf16(v, h, l);
        size_t o = (size_t)co * 1152 + tap * 128 + ci;
        bh[o] = h; bl[o] = l;
    } else if (bid < 3712) {              // ---- zero pad buffers
        const int lb  = bid - 3200;
        short* z = (lb < 128) ? z0 : (lb < 256) ? z1 : (lb < 384) ? z2 : z3;
        const short8 zero8 = {0,0,0,0,0,0,0,0};
        ((short8*)z)[(size_t)(lb & 127) * 256 + t] = zero8;
    } else {                              // ---- zero counters
        if (t < 32) cnt[t] = 0;
    }
}

// ---- unified split-bf16 MFMA implicit-GEMM conv + fused reduce -------------
// C[MTOT][128] = A*B ; A[m][k], k=tap*CIN+ci, A from padded NHWC [b][16][16][CIN]
// Block 128m x 128n, 4 waves (2x2 of 64x64), K-stage KSTEP, K-split S chunks.
// LDS: Sm[4][128][KSTEP] shorts, 16B chunk c stored at slot swz(row,c) so the
// wave's 32-row ds_read_b128 spreads across all bank groups (4-way floor).
// After partial write: device-fence + atomicAdd(cnt[mb]); the LAST block for
// this m-tile reduces all S partials -> bias+relu -> dn (+ padded bf16 hi/lo).
template<int POSN, int OW, int STR, int CIN, int MTOT, int KSTEP, int S, int PADOUT>
__global__ __launch_bounds__(256) void k_conv_red(const short* __restrict__ ah,
                                                  const short* __restrict__ al,
                                                  const short* __restrict__ bh,
                                                  const short* __restrict__ bl,
                                                  float* __restrict__ partial,
                                                  int* __restrict__ cnt,
                                                  const float* __restrict__ bias,
                                                  float* __restrict__ dn,
                                                  __hip_bfloat16* __restrict__ ph,
                                                  __hip_bfloat16* __restrict__ pl)
{
    constexpr int KTOT   = CIN * 9;
    constexpr int CHUNK  = KTOT / S;
    constexpr int NST    = CHUNK / KSTEP;
    constexpr int NCH    = KSTEP / 8;    // 16B chunks per row (8 or 4)
    constexpr int TPR    = NCH;          // threads per row
    constexpr int RPP    = 256 / TPR;    // rows per pass
    constexpr int PASSES = 128 / RPP;

    __shared__ short Sm[4][128][KSTEP];  // 0=AH 1=AL 2=BH 3=BL

    const int t    = threadIdx.x;
    const int lane = t & 63;
    const int w    = t >> 6;
    const int wm   = (w & 1) * 64;
    const int wn   = (w >> 1) * 64;
    const int lm   = lane & 31;
    const int half = lane >> 5;
    const int mb   = blockIdx.x;
    const int kc   = blockIdx.y;
    const int mbase = mb * 128;
    const int k0    = kc * CHUNK;

    auto swz = [](int row, int c) -> int {
        return (KSTEP == 64) ? (c ^ (row & 7)) : (c ^ ((row >> 1) & 3));
    };

    const int lr = t / TPR;              // row offset within pass
    const int ck = t % TPR;              // 16B chunk this thread stages
    int apos[PASSES]; bool aval[PASSES];
#pragma unroll
    for (int p = 0; p < PASSES; ++p) {
        int row = p * RPP + lr;
        int m   = mbase + row;
        aval[p] = (m < MTOT);
        int mm = aval[p] ? m : 0;
        int b  = mm / POSN;
        int pp = mm - b * POSN;
        int y  = pp / OW;
        int x  = pp - y * OW;
        apos[p] = b * 256 + y * STR * 16 + x * STR;
    }

    floatx16 acc[2][2];
#pragma unroll
    for (int mf = 0; mf < 2; ++mf)
#pragma unroll
        for (int nf = 0; nf < 2; ++nf)
#pragma unroll
            for (int r = 0; r < 16; ++r) acc[mf][nf][r] = 0.0f;

    const short8 zero8 = {0, 0, 0, 0, 0, 0, 0, 0};

    for (int st = 0; st < NST; ++st) {
        const int ks  = k0 + st * KSTEP;
        const int tap = ks / CIN;        // KSTEP-stage never straddles a tap
        const int ci0 = ks - tap * CIN;
        const int dy  = tap / 3, dx = tap - dy * 3;
        short8 vah[PASSES], val_[PASSES], vbh[PASSES], vbl[PASSES];
#pragma unroll
        for (int p = 0; p < PASSES; ++p) {
            int row = p * RPP + lr;
            if (aval[p]) {
                size_t g = (size_t)(apos[p] + dy * 16 + dx) * CIN + ci0 + ck * 8;
                vah[p] = *(const short8*)(ah + g);
                val_[p] = *(const short8*)(al + g);
            } else { vah[p] = zero8; val_[p] = zero8; }
            size_t gb = (size_t)row * KTOT + ks + ck * 8;
            vbh[p] = *(const short8*)(bh + gb);
            vbl[p] = *(const short8*)(bl + gb);
        }
#pragma unroll
        for (int p = 0; p < PASSES; ++p) {
            int row = p * RPP + lr;
            int sc  = swz(row, ck) * 8;
            *(short8*)&Sm[0][row][sc] = vah[p];
            *(short8*)&Sm[1][row][sc] = val_[p];
            *(short8*)&Sm[2][row][sc] = vbh[p];
            *(short8*)&Sm[3][row][sc] = vbl[p];
        }
        __syncthreads();
#pragma unroll
        for (int kst = 0; kst < KSTEP / 16; ++kst) {
            const int c = kst * 2 + half;
            short8 a_h[2], a_l[2], b_h[2], b_l[2];
#pragma unroll
            for (int mf = 0; mf < 2; ++mf) {
                int r = wm + mf * 32 + lm;
                int sc = swz(r, c) * 8;
                a_h[mf] = *(const short8*)&Sm[0][r][sc];
                a_l[mf] = *(const short8*)&Sm[1][r][sc];
            }
#pragma unroll
            for (int nf = 0; nf < 2; ++nf) {
                int r = wn + nf * 32 + lm;
                int sc = swz(r, c) * 8;
                b_h[nf] = *(const short8*)&Sm[2][r][sc];
                b_l[nf] = *(const short8*)&Sm[3][r][sc];
            }
#pragma unroll
            for (int mf = 0; mf < 2; ++mf)
#pragma unroll
                for (int nf = 0; nf < 2; ++nf) {
                    acc[mf][nf] = __builtin_amdgcn_mfma_f32_32x32x16_bf16(
                        a_h[mf], b_h[nf], acc[mf][nf], 0, 0, 0);
                    acc[mf][nf] = __builtin_amdgcn_mfma_f32_32x32x16_bf16(
                        a_h[mf], b_l[nf], acc[mf][nf], 0, 0, 0);
                    acc[mf][nf] = __builtin_amdgcn_mfma_f32_32x32x16_bf16(
                        a_l[mf], b_h[nf], acc[mf][nf], 0, 0, 0);
                }
        }
        __syncthreads();
    }

    float* P = partial + (size_t)kc * MTOT * 128;
#pragma unroll
    for (int mf = 0; mf < 2; ++mf)
#pragma unroll
        for (int nf = 0; nf < 2; ++nf)
#pragma unroll
            for (int r = 0; r < 16; ++r) {
                int row = (r & 3) + 8 * (r >> 2) + 4 * half;
                int m = mbase + wm + mf * 32 + row;
                int n = wn + nf * 32 + lm;
                if (m < MTOT) P[(size_t)m * 128 + n] = acc[mf][nf][r];
            }

    // ---- fused reduce: last block for this m-tile sums all S partials -----
    __threadfence();
    int* flagp = (int*)&Sm[0][0][0];     // Sm dead after last barrier
    if (t == 0) *flagp = (atomicAdd(cnt + mb, 1) == S - 1) ? 1 : 0;
    __syncthreads();
    if (!*flagp) return;
    __threadfence();
#pragma unroll 1
    for (int slot = t; slot < 128 * 32; slot += 256) {
        int row = slot >> 5;
        int c4  = slot & 31;
        int m   = mbase + row;
        if (m >= MTOT) continue;
        float4 s = ((const float4*)bias)[c4];
        for (int k = 0; k < S; ++k) {
            const float4 pv = *(const float4*)(partial +
                ((size_t)k * MTOT + m) * 128 + c4 * 4);
            s.x += pv.x; s.y += pv.y; s.z += pv.z; s.w += pv.w;
        }
        s.x = fmaxf(s.x, 0.0f); s.y = fmaxf(s.y, 0.0f);
        s.z = fmaxf(s.z, 0.0f); s.w = fmaxf(s.w, 0.0f);
        ((float4*)dn)[(size_t)m * 32 + c4] = s;
        if (PADOUT) {
            int b = m / POSN;
            int p = m - b * POSN;
            int y = p / OW;
            int x = p - y * OW;
            size_t pidx = (size_t)(b * 256 + (y + 1) * 16 + (x + 1)) * 32 + c4;
            ushort4 h, l;
            split_bf16(s.x, h.x, l.x);
            split_bf16(s.y, h.y, l.y);
            split_bf16(s.z, h.z, l.z);
            split_bf16(s.w, h.w, l.w);
            ((ushort4*)ph)[pidx] = h;
            ((ushort4*)pl)[pidx] = l;
        }
    }
}

// ---- fused 1x1 heads + greedy-NMS top-6 (one block per batch, 512 thr) ----
__global__ __launch_bounds__(512) void k_headnms(const float* __restrict__ d1n,
                                                 const float* __restrict__ d2n,
                                                 const float* __restrict__ d3n,
                                                 const float* __restrict__ w1, const float* __restrict__ b1,
                                                 const float* __restrict__ w2, const float* __restrict__ b2,
                                                 const float* __restrict__ w3, const float* __restrict__ b3,
                                                 const float* __restrict__ anchors,
                                                 float* __restrict__ out,
                                                 int* __restrict__ boxes)
{
    __shared__ float ms[NA];
    __shared__ float ay0[NA], ax0[NA], ay1[NA], ax1[NA];
    __shared__ unsigned char picked[NA];
    __shared__ float wsm[21 * 128];
    __shared__ float bsm[21];
    __shared__ float rv[8]; __shared__ int ri[8];
    __shared__ float win[5];
    const int b = blockIdx.x;
    const int t = threadIdx.x;

    for (int i = t; i < 21 * 128; i += 512)
        wsm[i] = (i < 768) ? w1[i] : (i < 1536) ? w2[i - 768] : w3[i - 1536];
    if (t < 21) bsm[t] = (t < 6) ? b1[t] : (t < 12) ? b2[t - 6] : b3[t - 12];
    for (int i = t; i < NA; i += 512) {
        float4 an = ((const float4*)anchors)[i];
        ay0[i] = an.x; ax0[i] = an.y; ay1[i] = an.z; ax1[i] = an.w;
        picked[i] = 0;
    }
    __syncthreads();

    for (int e = t; e < NA; e += 512) {
        const float* d; int wrow;
        if (e < 1176) {
            int c = e / 196, p = e - c * 196;
            d = d1n + (size_t)(b * 196 + p) * 128; wrow = c;
        } else if (e < 1470) {
            int e2 = e - 1176; int c = e2 / 49, p = e2 - c * 49;
            d = d2n + (size_t)(b * 49 + p) * 128; wrow = 6 + c;
        } else {
            int e2 = e - 1470; int c = e2 / 16, p = e2 - c * 16;
            d = d3n + (size_t)(b * 16 + p) * 128; wrow = 12 + c;
        }
        float s = bsm[wrow];
        const float4* wv4 = (const float4*)&wsm[wrow * 128];
#pragma unroll
        for (int i = 0; i < 32; ++i) {
            float4 dv = ((const float4*)d)[i];
            float4 wv = wv4[i];
            s = fmaf(dv.x, wv.x, s);
            s = fmaf(dv.y, wv.y, s);
            s = fmaf(dv.z, wv.z, s);
            s = fmaf(dv.w, wv.w, s);
        }
        ms[e] = s;
    }
    __syncthreads();

    for (int r = 0; r < 6; ++r) {
        float bv = -INFINITY; int bi = NA;
        for (int i = t; i < NA; i += 512) {
            if (!picked[i]) {
                float v = ms[i];
                if (v > bv || (v == bv && i < bi)) { bv = v; bi = i; }
            }
        }
#pragma unroll
        for (int off = 32; off > 0; off >>= 1) {
            float v2 = __shfl_down(bv, off);
            int   i2 = __shfl_down(bi, off);
            if (v2 > bv || (v2 == bv && i2 < bi)) { bv = v2; bi = i2; }
        }
        if ((t & 63) == 0) { rv[t >> 6] = bv; ri[t >> 6] = bi; }
        __syncthreads();
        if (t == 0) {
            bv = rv[0]; bi = ri[0];
            for (int wv = 1; wv < 8; ++wv)
                if (rv[wv] > bv || (rv[wv] == bv && ri[wv] < bi)) { bv = rv[wv]; bi = ri[wv]; }
            picked[bi] = 1;
            win[0] = ay0[bi]; win[1] = ax0[bi]; win[2] = ay1[bi]; win[3] = ax1[bi]; win[4] = bv;
            int o = b * 6 + r;
            out[OFF_COORDS + o * 4 + 0] = ax0[bi];
            out[OFF_COORDS + o * 4 + 1] = ay0[bi];
            out[OFF_COORDS + o * 4 + 2] = ax1[bi];
            out[OFF_COORDS + o * 4 + 3] = ay1[bi];
            out[OFF_PROB + o] = bv;
            out[OFF_IDX  + o] = (float)bi;
            boxes[o * 4 + 0] = (int)ax0[bi];
            boxes[o * 4 + 1] = (int)ay0[bi];
            boxes[o * 4 + 2] = (int)ax1[bi];
            boxes[o * 4 + 3] = (int)ay1[bi];
        }
        __syncthreads();
        float by0 = win[0], bx0 = win[1], by1 = win[2], bx1 = win[3];
        float barea = (by1 - by0) * (bx1 - bx0);
        for (int i = t; i < NA; i += 512) {
            if (picked[i]) continue;
            float ih = fmaxf(fminf(by1, ay1[i]) - fmaxf(by0, ay0[i]), 0.0f);
            float iw = fmaxf(fminf(bx1, ax1[i]) - fmaxf(bx0, ax0[i]), 0.0f);
            float inter = ih * iw;
            float area  = (ay1[i] - ay0[i]) * (ax1[i] - ax0[i]);
            float iou = inter / (barea + area - inter);
            if (iou > 0.25f) ms[i] = -INFINITY;
        }
        __syncthreads();
    }
}

// ---- bilinear crop-resize (flat index, all lanes used) ---------------------
__global__ __launch_bounds__(256) void k_crop(const float* __restrict__ x,
                                              const int* __restrict__ boxes,
                                              float* __restrict__ out)
{
    int idx = blockIdx.x * 256 + threadIdx.x;       // < 48*3*224*224
    int i   = idx % 224;
    int j   = (idx / 224) % 224;
    int rem = idx / 50176;
    int c   = rem % 3;
    int br  = rem / 3;
    int b   = br / 6;
    int4 bx = ((const int4*)boxes)[br];
    float tj = (float)j / 223.0f;
    float sy = (float)bx.y + tj * (float)(bx.w - 1 - bx.y);
    int y0i = (int)floorf(sy);
    int y1i = min(y0i + 1, bx.w - 1);
    float wy = sy - (float)y0i;
    float ti = (float)i / 223.0f;
    float sx = (float)bx.x + ti * (float)(bx.z - 1 - bx.x);
    int x0i = (int)floorf(sx);
    int x1i = min(x0i + 1, bx.z - 1);
    float wx = sx - (float)x0i;
    const float* img = x + ((size_t)b * 3 + c) * 448 * 448;
    auto g = [&](int yy, int xx) -> float {
        yy -= 224; xx -= 224;
        if ((unsigned)yy >= 448u || (unsigned)xx >= 448u) return 0.0f;
        return img[(size_t)yy * 448 + xx];
    };
    float g00 = g(y0i, x0i), g01 = g(y0i, x1i);
    float g10 = g(y1i, x0i), g11 = g(y1i, x1i);
    float top = (1.0f - wx) * g00 + wx * g01;
    float bot = (1.0f - wx) * g10 + wx * g11;
    out[idx] = (1.0f - wy) * top + wy * bot;
}

// ---------------------------------------------------------------------------
extern "C" void kernel_launch(void* const* d_in, const int* in_sizes, int n_in,
                              void* d_out, int out_size, void* d_ws, size_t ws_size,
                              hipStream_t stream)
{
    (void)in_sizes; (void)n_in; (void)out_size; (void)ws_size;
    const float* x    = (const float*)d_in[0];
    const float* rpn  = (const float*)d_in[1];
    const float* anch = (const float*)d_in[2];
    const float* wd1  = (const float*)d_in[3];
    const float* bd1  = (const float*)d_in[4];
    const float* wd2  = (const float*)d_in[5];
    const float* bd2  = (const float*)d_in[6];
    const float* wd3  = (const float*)d_in[7];
    const float* bd3  = (const float*)d_in[8];
    const float* hw1  = (const float*)d_in[9];
    const float* hb1  = (const float*)d_in[10];
    const float* hw2  = (const float*)d_in[11];
    const float* hb2  = (const float*)d_in[12];
    const float* hw3  = (const float*)d_in[13];
    const float* hb3  = (const float*)d_in[14];
    float* out = (float*)d_out;

    char* ws = (char*)d_ws;
    size_t off = 0;
    auto alloc = [&](size_t bytes) -> void* {
        void* p = ws + off;
        off = (off + bytes + 255) & ~(size_t)255;
        return p;
    };
    unsigned short* ahb = (unsigned short*)alloc((size_t)8 * 256 * 2048 * 2);
    unsigned short* alb = (unsigned short*)alloc((size_t)8 * 256 * 2048 * 2);
    unsigned short* b1h = (unsigned short*)alloc((size_t)128 * K1TOT * 2);
    unsigned short* b1l = (unsigned short*)alloc((size_t)128 * K1TOT * 2);
    unsigned short* b2h = (unsigned short*)alloc((size_t)128 * 1152 * 2);
    unsigned short* b2l = (unsigned short*)alloc((size_t)128 * 1152 * 2);
    unsigned short* b3h = (unsigned short*)alloc((size_t)128 * 1152 * 2);
    unsigned short* b3l = (unsigned short*)alloc((size_t)128 * 1152 * 2);
    __hip_bfloat16* d1ph = (__hip_bfloat16*)alloc((size_t)8 * 256 * 128 * 2);
    __hip_bfloat16* d1pl = (__hip_bfloat16*)alloc((size_t)8 * 256 * 128 * 2);
    __hip_bfloat16* d2ph = (__hip_bfloat16*)alloc((size_t)8 * 256 * 128 * 2);
    __hip_bfloat16* d2pl = (__hip_bfloat16*)alloc((size_t)8 * 256 * 128 * 2);
    float* d1n  = (float*)alloc((size_t)8 * 196 * 128 * 4);
    float* d2n  = (float*)alloc((size_t)8 * 49 * 128 * 4);
    float* d3n  = (float*)alloc((size_t)8 * 16 * 128 * 4);
    int*   cnt  = (int*)alloc(32 * 4);
    int*  boxes = (int*)alloc((size_t)8 * 6 * 4 * 4);
    float* P    = (float*)alloc((size_t)48 * 1568 * 128 * 4);

    // 1) unified prep (weights, conv1 input, pad-zeroing, counters)
    k_prep<<<dim3(3713), 256, 0, stream>>>(rpn, wd1, wd2, wd3,
        ahb, alb, b1h, b1l, b2h, b2l, b3h, b3l,
        (short*)d1ph, (short*)d1pl, (short*)d2ph, (short*)d2pl, cnt);

    // 2) conv1 + reduce: M=1568, CIN=2048, KSTEP=64, S=48 (chunk 384, 6 iters)
    k_conv_red<196, 14, 1, 2048, 1568, 64, 48, 1><<<dim3(13, 48), 256, 0, stream>>>(
        (const short*)ahb, (const short*)alb, (const short*)b1h, (const short*)b1l,
        P, cnt, bd1, d1n, d1ph, d1pl);

    // 3) conv2 + reduce: M=392, CIN=128, KSTEP=32, S=36 (chunk 32, 1 iter)
    k_conv_red<49, 7, 2, 128, 392, 32, 36, 1><<<dim3(4, 36), 256, 0, stream>>>(
        (const short*)d1ph, (const short*)d1pl, (const short*)b2h, (const short*)b2l,
        P, cnt + 16, bd2, d2n, d2ph, d2pl);

    // 4) conv3 + reduce: M=128, CIN=128, KSTEP=32, S=36
    k_conv_red<16, 4, 2, 128, 128, 32, 36, 0><<<dim3(1, 36), 256, 0, stream>>>(
        (const short*)d2ph, (const short*)d2pl, (const short*)b3h, (const short*)b3l,
        P, cnt + 24, bd3, d3n, nullptr, nullptr);

    // 5) heads + NMS fused (scores live entirely in LDS)
    k_headnms<<<dim3(8), 512, 0, stream>>>(d1n, d2n, d3n,
        hw1, hb1, hw2, hb2, hw3, hb3, anch, out, boxes);

    // 6) bilinear crop
    k_crop<<<dim3(28224), 256, 0, stream>>>(x, boxes, out);
}

// Round 4
// 276.646 us; speedup vs baseline: 1.5658x; 1.5658x over previous
//
#include <hip/hip_runtime.h>
#include <hip/hip_bf16.h>
#include <math.h>
#include <stdint.h>

// ---------------------------------------------------------------------------
// attention_net (MI355X gfx950)
//   conv1: 2048->128 14x14 s1p1 | conv2: 128->128 ->7x7 s2p1 | conv3: ->4x4
//   All three convs: split-bf16 (hi+lo) MFMA 32x32x16, NHWC padded-16x16 A.
//   Then 1x1 heads -> scores(8,1614) -> greedy-NMS top6 -> bilinear crop.
// R4: R0 conv structure (fastest known) with 64-row m-tiles / 2-wave /
//     128-thread blocks -> 2x resident blocks per CU (TLP for latency
//     hiding). Separate vectorized reduce kernels (R3's fused-reduce tail
//     was 130us serial -- reverted). Keep R3's verified unified prep,
//     fused heads+NMS, flat crop (9 dispatches).
// Output floats: part_imgs[7225344], coords[192], top_prob[48], top_idx[48]
// ---------------------------------------------------------------------------

#define OFF_COORDS 7225344
#define OFF_PROB   7225536
#define OFF_IDX    7225584
#define NA 1614
#define K1TOT 18432

typedef __attribute__((ext_vector_type(8)))  short  short8;
typedef __attribute__((ext_vector_type(16))) float  floatx16;

__device__ inline void split_bf16(float v, unsigned short& h, unsigned short& l)
{
    __hip_bfloat16 hb = __float2bfloat16(v);
    float hv = __bfloat162float(hb);
    __hip_bfloat16 lb = __float2bfloat16(v - hv);
    h = *reinterpret_cast<unsigned short*>(&hb);
    l = *reinterpret_cast<unsigned short*>(&lb);
}

// ---- unified prep: 3200 blocks ---------------------------------------------
//  [0,1024)      prep_a : rpn NCHW fp32 -> padded NHWC split-bf16
//  [1024,2048)   prep_b1: wd1 -> b1 [co][tap*2048+ci] split-bf16 (LDS transpose)
//  [2048,3200)   prep_w23: wd2/wd3 -> b2/b3 [co][tap*128+ci]
__global__ __launch_bounds__(256) void k_prep(const float* __restrict__ rpn,
                                              const float* __restrict__ w1,
                                              const float* __restrict__ w2,
                                              const float* __restrict__ w3,
                                              unsigned short* __restrict__ ah,
                                              unsigned short* __restrict__ al,
                                              unsigned short* __restrict__ b1h,
                                              unsigned short* __restrict__ b1l,
                                              unsigned short* __restrict__ b2h,
                                              unsigned short* __restrict__ b2l,
                                              unsigned short* __restrict__ b3h,
                                              unsigned short* __restrict__ b3l)
{
    __shared__ float tileA[64][65];
    __shared__ float tileB[9][260];
    const int bid = blockIdx.x;
    const int t   = threadIdx.x;

    if (bid < 1024) {                     // ---- prep_a
        const int cib  = (bid & 31) * 64;
        const int posb = ((bid >> 5) & 3) * 64;
        const int b    = bid >> 7;
#pragma unroll
        for (int it = 0; it < 16; ++it) {
            int idx  = it * 256 + t;
            int cil  = idx >> 6;
            int posl = idx & 63;
            int pos  = posb + posl;
            int py = pos >> 4, px = pos & 15;
            int y = py - 1, x = px - 1;
            float v = 0.0f;
            if ((unsigned)y < 14u && (unsigned)x < 14u)
                v = rpn[((size_t)(b * 2048 + cib + cil) * 14 + y) * 14 + x];
            tileA[cil][posl] = v;
        }
        __syncthreads();
#pragma unroll
        for (int it = 0; it < 16; ++it) {
            int idx  = it * 256 + t;
            int posl = idx >> 6;
            int cil  = idx & 63;
            float v = tileA[cil][posl];
            unsigned short h, l;
            split_bf16(v, h, l);
            size_t o = (size_t)(b * 256 + posb + posl) * 2048 + cib + cil;
            ah[o] = h; al[o] = l;
        }
    } else if (bid < 2048) {              // ---- prep_b (conv1)
        const int lb  = bid - 1024;
        const int ci0 = (lb & 7) * 256;
        const int co  = lb >> 3;
        const float* wc = w1 + (size_t)co * K1TOT + (size_t)ci0 * 9;
#pragma unroll
        for (int it = 0; it < 9; ++it) {
            int i = it * 256 + t;
            float v = wc[i];
            tileB[i % 9][i / 9] = v;
        }
        __syncthreads();
#pragma unroll
        for (int tap = 0; tap < 9; ++tap) {
            float v = tileB[tap][t];
            unsigned short h, l;
            split_bf16(v, h, l);
            size_t o = (size_t)co * K1TOT + (size_t)tap * 2048 + ci0 + t;
            b1h[o] = h; b1l[o] = l;
        }
    } else {                              // ---- prep_w23
        const int lb  = bid - 2048;
        const int tap = lb % 9;
        const int co  = lb / 9;
        const int z   = t >> 7;
        const int ci  = t & 127;
        const float* w = z ? w3 : w2;
        unsigned short* bh = z ? b3h : b2h;
        unsigned short* bl = z ? b3l : b2l;
        float v = w[((size_t)co * 128 + ci) * 9 + tap];
        unsigned short h, l;
        split_bf16(v, h, l);
        size_t o = (size_t)co * 1152 + tap * 128 + ci;
        bh[o] = h; bl[o] = l;
    }
}

// ---- split-bf16 MFMA implicit-GEMM conv, 64-row m-tile, 2 waves -----------
// C[MTOT][128] = A*B ; A[m][k], k=tap*CIN+ci, A from padded NHWC [b][16][16][CIN]
// Block 64m x 128n, 2 waves (each 64m x 64n), K-stage 32, K-split grid.y.
// R0-proven schedule: load -> ds_write -> sync -> 2x12 MFMA -> sync.
// LDS 30.7KB/block -> 5 blocks/CU; grid 25x48=1200 -> ~4.7 blocks/CU (TLP).
template<int POSN, int OW, int STR, int CIN, int MTOT>
__global__ __launch_bounds__(128) void k_conv64(const short* __restrict__ ah,
                                                const short* __restrict__ al,
                                                const short* __restrict__ bh,
                                                const short* __restrict__ bl,
                                                float* __restrict__ partial,
                                                int chunk)
{
    constexpr int KTOT = CIN * 9;
    __shared__ short AsH[64][40];
    __shared__ short AsL[64][40];
    __shared__ short BsH[128][40];
    __shared__ short BsL[128][40];

    const int t     = threadIdx.x;
    const int lane  = t & 63;
    const int w     = t >> 6;            // 0..1
    const int wn    = w * 64;
    const int lm    = lane & 31;
    const int half  = lane >> 5;
    const int mbase = blockIdx.x * 64;
    const int kc    = blockIdx.y;
    const int k0    = kc * chunk;
    const int k1    = (k0 + chunk < KTOT) ? (k0 + chunk) : KTOT;

    const int akc = (t & 3) * 8;         // 16B chunk offset within 32-k stage
    int arow[2], apos[2]; bool aval[2];
#pragma unroll
    for (int i = 0; i < 2; ++i) {
        int slot = i * 128 + t;
        int row  = slot >> 2;            // 0..63
        int m    = mbase + row;
        arow[i] = row;
        aval[i] = (m < MTOT);
        int mm = aval[i] ? m : 0;
        int b  = mm / POSN;
        int p  = mm - b * POSN;
        int y  = p / OW;
        int x  = p - y * OW;
        apos[i] = b * 256 + y * STR * 16 + x * STR;
    }

    floatx16 acc[2][2];
#pragma unroll
    for (int mf = 0; mf < 2; ++mf)
#pragma unroll
        for (int nf = 0; nf < 2; ++nf)
#pragma unroll
            for (int r = 0; r < 16; ++r) acc[mf][nf][r] = 0.0f;

    const short8 zero8 = {0, 0, 0, 0, 0, 0, 0, 0};

    for (int ks = k0; ks < k1; ks += 32) {
        const int tap = ks / CIN;        // stage (32) never straddles a tap
        const int ci0 = ks - tap * CIN;
        const int dy  = tap / 3, dx = tap - dy * 3;
#pragma unroll
        for (int i = 0; i < 2; ++i) {
            short8 vh = zero8, vl = zero8;
            if (aval[i]) {
                size_t g = (size_t)(apos[i] + dy * 16 + dx) * CIN + ci0 + akc;
                vh = *(const short8*)(ah + g);
                vl = *(const short8*)(al + g);
            }
            *(short8*)&AsH[arow[i]][akc] = vh;
            *(short8*)&AsL[arow[i]][akc] = vl;
        }
#pragma unroll
        for (int j = 0; j < 4; ++j) {
            int n = ((j * 128 + t) >> 2);    // 0..127
            size_t g = (size_t)n * KTOT + ks + akc;
            *(short8*)&BsH[n][akc] = *(const short8*)(bh + g);
            *(short8*)&BsL[n][akc] = *(const short8*)(bl + g);
        }
        __syncthreads();
#pragma unroll
        for (int kst = 0; kst < 2; ++kst) {
            const int koff = kst * 16 + half * 8;
            short8 a_h[2], a_l[2], b_h[2], b_l[2];
#pragma unroll
            for (int mf = 0; mf < 2; ++mf) {
                a_h[mf] = *(const short8*)&AsH[mf * 32 + lm][koff];
                a_l[mf] = *(const short8*)&AsL[mf * 32 + lm][koff];
            }
#pragma unroll
            for (int nf = 0; nf < 2; ++nf) {
                b_h[nf] = *(const short8*)&BsH[wn + nf * 32 + lm][koff];
                b_l[nf] = *(const short8*)&BsL[wn + nf * 32 + lm][koff];
            }
#pragma unroll
            for (int mf = 0; mf < 2; ++mf)
#pragma unroll
                for (int nf = 0; nf < 2; ++nf) {
                    acc[mf][nf] = __builtin_amdgcn_mfma_f32_32x32x16_bf16(
                        a_h[mf], b_h[nf], acc[mf][nf], 0, 0, 0);
                    acc[mf][nf] = __builtin_amdgcn_mfma_f32_32x32x16_bf16(
                        a_h[mf], b_l[nf], acc[mf][nf], 0, 0, 0);
                    acc[mf][nf] = __builtin_amdgcn_mfma_f32_32x32x16_bf16(
                        a_l[mf], b_h[nf], acc[mf][nf], 0, 0, 0);
                }
        }
        __syncthreads();
    }

    float* P = partial + (size_t)kc * MTOT * 128;
#pragma unroll
    for (int mf = 0; mf < 2; ++mf)
#pragma unroll
        for (int nf = 0; nf < 2; ++nf)
#pragma unroll
            for (int r = 0; r < 16; ++r) {
                int row = (r & 3) + 8 * (r >> 2) + 4 * half;
                int m = mbase + mf * 32 + row;
                int n = wn + nf * 32 + lm;
                if (m < MTOT) P[(size_t)m * 128 + n] = acc[mf][nf][r];
            }
}

// ---- fused reduce: partials + bias + relu -> NHWC fp32 + padded bf16 hi/lo
template<int POSN, int OWV>
__global__ __launch_bounds__(256) void k_reduce_pad(const float* __restrict__ partial,
                                                    const float* __restrict__ bias,
                                                    float* __restrict__ dn,
                                                    __hip_bfloat16* __restrict__ ph,
                                                    __hip_bfloat16* __restrict__ pl,
                                                    int S)
{
    constexpr int MTOT = 8 * POSN;
    int idx = blockIdx.x * 256 + threadIdx.x;   // < 8*256*32
    int b   = idx >> 13;
    int pos = (idx >> 5) & 255;
    int c4  = idx & 31;
    int y = (pos >> 4) - 1;
    int x = (pos & 15) - 1;
    if ((unsigned)y < (unsigned)OWV && (unsigned)x < (unsigned)OWV) {
        int m = b * POSN + y * OWV + x;
        float4 s = ((const float4*)bias)[c4];
        for (int k = 0; k < S; ++k) {
            float4 p = ((const float4*)(partial + (size_t)k * MTOT * 128 + (size_t)m * 128))[c4];
            s.x += p.x; s.y += p.y; s.z += p.z; s.w += p.w;
        }
        s.x = fmaxf(s.x, 0.0f); s.y = fmaxf(s.y, 0.0f);
        s.z = fmaxf(s.z, 0.0f); s.w = fmaxf(s.w, 0.0f);
        ((float4*)dn)[(size_t)m * 32 + c4] = s;
        ushort4 h, l;
        split_bf16(s.x, h.x, l.x);
        split_bf16(s.y, h.y, l.y);
        split_bf16(s.z, h.z, l.z);
        split_bf16(s.w, h.w, l.w);
        ((ushort4*)ph)[idx] = h;
        ((ushort4*)pl)[idx] = l;
    } else {
        ushort4 z = {0, 0, 0, 0};
        ((ushort4*)ph)[idx] = z;
        ((ushort4*)pl)[idx] = z;
    }
}

// ---- reduce conv3 (no pad output) -> NHWC fp32 [8][16][128], float4 -------
__global__ __launch_bounds__(256) void k_reduce3(const float* __restrict__ partial,
                                                 const float* __restrict__ bias,
                                                 float* __restrict__ dn, int S)
{
    int idx = blockIdx.x * 256 + threadIdx.x;   // < 4096 float4 slots
    int c4  = idx & 31;
    float4 s = ((const float4*)bias)[c4];
    for (int k = 0; k < S; ++k) {
        float4 p = ((const float4*)(partial + (size_t)k * 128 * 128))[idx];
        s.x += p.x; s.y += p.y; s.z += p.z; s.w += p.w;
    }
    s.x = fmaxf(s.x, 0.0f); s.y = fmaxf(s.y, 0.0f);
    s.z = fmaxf(s.z, 0.0f); s.w = fmaxf(s.w, 0.0f);
    ((float4*)dn)[idx] = s;
}

// ---- fused 1x1 heads + greedy-NMS top-6 (one block per batch, 512 thr) ----
__global__ __launch_bounds__(512) void k_headnms(const float* __restrict__ d1n,
                                                 const float* __restrict__ d2n,
                                                 const float* __restrict__ d3n,
                                                 const float* __restrict__ w1, const float* __restrict__ b1,
                                                 const float* __restrict__ w2, const float* __restrict__ b2,
                                                 const float* __restrict__ w3, const float* __restrict__ b3,
                                                 const float* __restrict__ anchors,
                                                 float* __restrict__ out,
                                                 int* __restrict__ boxes)
{
    __shared__ float ms[NA];
    __shared__ float ay0[NA], ax0[NA], ay1[NA], ax1[NA];
    __shared__ unsigned char picked[NA];
    __shared__ float wsm[21 * 128];
    __shared__ float bsm[21];
    __shared__ float rv[8]; __shared__ int ri[8];
    __shared__ float win[5];
    const int b = blockIdx.x;
    const int t = threadIdx.x;

    for (int i = t; i < 21 * 128; i += 512)
        wsm[i] = (i < 768) ? w1[i] : (i < 1536) ? w2[i - 768] : w3[i - 1536];
    if (t < 21) bsm[t] = (t < 6) ? b1[t] : (t < 12) ? b2[t - 6] : b3[t - 12];
    for (int i = t; i < NA; i += 512) {
        float4 an = ((const float4*)anchors)[i];
        ay0[i] = an.x; ax0[i] = an.y; ay1[i] = an.z; ax1[i] = an.w;
        picked[i] = 0;
    }
    __syncthreads();

    for (int e = t; e < NA; e += 512) {
        const float* d; int wrow;
        if (e < 1176) {
            int c = e / 196, p = e - c * 196;
            d = d1n + (size_t)(b * 196 + p) * 128; wrow = c;
        } else if (e < 1470) {
            int e2 = e - 1176; int c = e2 / 49, p = e2 - c * 49;
            d = d2n + (size_t)(b * 49 + p) * 128; wrow = 6 + c;
        } else {
            int e2 = e - 1470; int c = e2 / 16, p = e2 - c * 16;
            d = d3n + (size_t)(b * 16 + p) * 128; wrow = 12 + c;
        }
        float s = bsm[wrow];
        const float4* wv4 = (const float4*)&wsm[wrow * 128];
#pragma unroll
        for (int i = 0; i < 32; ++i) {
            float4 dv = ((const float4*)d)[i];
            float4 wv = wv4[i];
            s = fmaf(dv.x, wv.x, s);
            s = fmaf(dv.y, wv.y, s);
            s = fmaf(dv.z, wv.z, s);
            s = fmaf(dv.w, wv.w, s);
        }
        ms[e] = s;
    }
    __syncthreads();

    for (int r = 0; r < 6; ++r) {
        float bv = -INFINITY; int bi = NA;
        for (int i = t; i < NA; i += 512) {
            if (!picked[i]) {
                float v = ms[i];
                if (v > bv || (v == bv && i < bi)) { bv = v; bi = i; }
            }
        }
#pragma unroll
        for (int off = 32; off > 0; off >>= 1) {
            float v2 = __shfl_down(bv, off);
            int   i2 = __shfl_down(bi, off);
            if (v2 > bv || (v2 == bv && i2 < bi)) { bv = v2; bi = i2; }
        }
        if ((t & 63) == 0) { rv[t >> 6] = bv; ri[t >> 6] = bi; }
        __syncthreads();
        if (t == 0) {
            bv = rv[0]; bi = ri[0];
            for (int wv = 1; wv < 8; ++wv)
                if (rv[wv] > bv || (rv[wv] == bv && ri[wv] < bi)) { bv = rv[wv]; bi = ri[wv]; }
            picked[bi] = 1;
            win[0] = ay0[bi]; win[1] = ax0[bi]; win[2] = ay1[bi]; win[3] = ax1[bi]; win[4] = bv;
            int o = b * 6 + r;
            out[OFF_COORDS + o * 4 + 0] = ax0[bi];
            out[OFF_COORDS + o * 4 + 1] = ay0[bi];
            out[OFF_COORDS + o * 4 + 2] = ax1[bi];
            out[OFF_COORDS + o * 4 + 3] = ay1[bi];
            out[OFF_PROB + o] = bv;
            out[OFF_IDX  + o] = (float)bi;
            boxes[o * 4 + 0] = (int)ax0[bi];
            boxes[o * 4 + 1] = (int)ay0[bi];
            boxes[o * 4 + 2] = (int)ax1[bi];
            boxes[o * 4 + 3] = (int)ay1[bi];
        }
        __syncthreads();
        float by0 = win[0], bx0 = win[1], by1 = win[2], bx1 = win[3];
        float barea = (by1 - by0) * (bx1 - bx0);
        for (int i = t; i < NA; i += 512) {
            if (picked[i]) continue;
            float ih = fmaxf(fminf(by1, ay1[i]) - fmaxf(by0, ay0[i]), 0.0f);
            float iw = fmaxf(fminf(bx1, ax1[i]) - fmaxf(bx0, ax0[i]), 0.0f);
            float inter = ih * iw;
            float area  = (ay1[i] - ay0[i]) * (ax1[i] - ax0[i]);
            float iou = inter / (barea + area - inter);
            if (iou > 0.25f) ms[i] = -INFINITY;
        }
        __syncthreads();
    }
}

// ---- bilinear crop-resize (flat index, all lanes used) ---------------------
__global__ __launch_bounds__(256) void k_crop(const float* __restrict__ x,
                                              const int* __restrict__ boxes,
                                              float* __restrict__ out)
{
    int idx = blockIdx.x * 256 + threadIdx.x;       // < 48*3*224*224
    int i   = idx % 224;
    int j   = (idx / 224) % 224;
    int rem = idx / 50176;
    int c   = rem % 3;
    int br  = rem / 3;
    int b   = br / 6;
    int4 bx = ((const int4*)boxes)[br];
    float tj = (float)j / 223.0f;
    float sy = (float)bx.y + tj * (float)(bx.w - 1 - bx.y);
    int y0i = (int)floorf(sy);
    int y1i = min(y0i + 1, bx.w - 1);
    float wy = sy - (float)y0i;
    float ti = (float)i / 223.0f;
    float sx = (float)bx.x + ti * (float)(bx.z - 1 - bx.x);
    int x0i = (int)floorf(sx);
    int x1i = min(x0i + 1, bx.z - 1);
    float wx = sx - (float)x0i;
    const float* img = x + ((size_t)b * 3 + c) * 448 * 448;
    auto g = [&](int yy, int xx) -> float {
        yy -= 224; xx -= 224;
        if ((unsigned)yy >= 448u || (unsigned)xx >= 448u) return 0.0f;
        return img[(size_t)yy * 448 + xx];
    };
    float g00 = g(y0i, x0i), g01 = g(y0i, x1i);
    float g10 = g(y1i, x0i), g11 = g(y1i, x1i);
    float top = (1.0f - wx) * g00 + wx * g01;
    float bot = (1.0f - wx) * g10 + wx * g11;
    out[idx] = (1.0f - wy) * top + wy * bot;
}

// ---------------------------------------------------------------------------
extern "C" void kernel_launch(void* const* d_in, const int* in_sizes, int n_in,
                              void* d_out, int out_size, void* d_ws, size_t ws_size,
                              hipStream_t stream)
{
    (void)in_sizes; (void)n_in; (void)out_size;
    const float* x    = (const float*)d_in[0];
    const float* rpn  = (const float*)d_in[1];
    const float* anch = (const float*)d_in[2];
    const float* wd1  = (const float*)d_in[3];
    const float* bd1  = (const float*)d_in[4];
    const float* wd2  = (const float*)d_in[5];
    const float* bd2  = (const float*)d_in[6];
    const float* wd3  = (const float*)d_in[7];
    const float* bd3  = (const float*)d_in[8];
    const float* hw1  = (const float*)d_in[9];
    const float* hb1  = (const float*)d_in[10];
    const float* hw2  = (const float*)d_in[11];
    const float* hb2  = (const float*)d_in[12];
    const float* hw3  = (const float*)d_in[13];
    const float* hb3  = (const float*)d_in[14];
    float* out = (float*)d_out;

    char* ws = (char*)d_ws;
    size_t off = 0;
    auto alloc = [&](size_t bytes) -> void* {
        void* p = ws + off;
        off = (off + bytes + 255) & ~(size_t)255;
        return p;
    };
    unsigned short* ahb = (unsigned short*)alloc((size_t)8 * 256 * 2048 * 2);
    unsigned short* alb = (unsigned short*)alloc((size_t)8 * 256 * 2048 * 2);
    unsigned short* b1h = (unsigned short*)alloc((size_t)128 * K1TOT * 2);
    unsigned short* b1l = (unsigned short*)alloc((size_t)128 * K1TOT * 2);
    unsigned short* b2h = (unsigned short*)alloc((size_t)128 * 1152 * 2);
    unsigned short* b2l = (unsigned short*)alloc((size_t)128 * 1152 * 2);
    unsigned short* b3h = (unsigned short*)alloc((size_t)128 * 1152 * 2);
    unsigned short* b3l = (unsigned short*)alloc((size_t)128 * 1152 * 2);
    __hip_bfloat16* d1ph = (__hip_bfloat16*)alloc((size_t)8 * 256 * 128 * 2);
    __hip_bfloat16* d1pl = (__hip_bfloat16*)alloc((size_t)8 * 256 * 128 * 2);
    __hip_bfloat16* d2ph = (__hip_bfloat16*)alloc((size_t)8 * 256 * 128 * 2);
    __hip_bfloat16* d2pl = (__hip_bfloat16*)alloc((size_t)8 * 256 * 128 * 2);
    float* d1n  = (float*)alloc((size_t)8 * 196 * 128 * 4);
    float* d2n  = (float*)alloc((size_t)8 * 49 * 128 * 4);
    float* d3n  = (float*)alloc((size_t)8 * 16 * 128 * 4);
    int*  boxes = (int*)alloc((size_t)8 * 6 * 4 * 4);
    size_t avail = (ws_size > off) ? (ws_size - off) : 0;
    float* P = (float*)(ws + off);

    long long s1 = (long long)(avail / ((size_t)1568 * 128 * 4));
    if (s1 > 48) s1 = 48;
    if (s1 < 1)  s1 = 1;
    int S1 = (int)s1;
    int chunk1 = ((K1TOT + S1 * 32 - 1) / (S1 * 32)) * 32;

    long long s2 = (long long)(avail / ((size_t)392 * 128 * 4));
    if (s2 > 36) s2 = 36;
    if (s2 < 1)  s2 = 1;
    int S2 = (int)s2;
    int chunk2 = ((1152 + S2 * 32 - 1) / (S2 * 32)) * 32;

    long long s3 = (long long)(avail / ((size_t)128 * 128 * 4));
    if (s3 > 36) s3 = 36;
    if (s3 < 1)  s3 = 1;
    int S3 = (int)s3;
    int chunk3 = ((1152 + S3 * 32 - 1) / (S3 * 32)) * 32;

    // 1) unified prep (weights + conv1 input)
    k_prep<<<dim3(3200), 256, 0, stream>>>(rpn, wd1, wd2, wd3,
        ahb, alb, b1h, b1l, b2h, b2l, b3h, b3l);

    // 2) conv1: M=1568, CIN=2048, 64-row tiles, grid 25 x S1
    k_conv64<196, 14, 1, 2048, 1568><<<dim3(25, S1), 128, 0, stream>>>(
        (const short*)ahb, (const short*)alb, (const short*)b1h, (const short*)b1l, P, chunk1);
    k_reduce_pad<196, 14><<<dim3(256), 256, 0, stream>>>(P, bd1, d1n, d1ph, d1pl, S1);

    // 3) conv2: M=392, CIN=128, K=1152, 64-row tiles, grid 7 x S2
    k_conv64<49, 7, 2, 128, 392><<<dim3(7, S2), 128, 0, stream>>>(
        (const short*)d1ph, (const short*)d1pl, (const short*)b2h, (const short*)b2l, P, chunk2);
    k_reduce_pad<49, 7><<<dim3(256), 256, 0, stream>>>(P, bd2, d2n, d2ph, d2pl, S2);

    // 4) conv3: M=128, CIN=128, K=1152, 64-row tiles, grid 2 x S3
    k_conv64<16, 4, 2, 128, 128><<<dim3(2, S3), 128, 0, stream>>>(
        (const short*)d2ph, (const short*)d2pl, (const short*)b3h, (const short*)b3l, P, chunk3);
    k_reduce3<<<dim3(16), 256, 0, stream>>>(P, bd3, d3n, S3);

    // 5) heads + NMS fused (scores live entirely in LDS)
    k_headnms<<<dim3(8), 512, 0, stream>>>(d1n, d2n, d3n,
        hw1, hb1, hw2, hb2, hw3, hb3, anch, out, boxes);

    // 6) bilinear crop
    k_crop<<<dim3(28224), 256, 0, stream>>>(x, boxes, out);
}

// Round 5
// 253.728 us; speedup vs baseline: 1.7072x; 1.0903x over previous
//
#include <hip/hip_runtime.h>
#include <hip/hip_bf16.h>
#include <math.h>
#include <stdint.h>

// ---------------------------------------------------------------------------
// attention_net (MI355X gfx950)
//   conv1: 2048->128 14x14 s1p1 | conv2: 128->128 ->7x7 s2p1 | conv3: ->4x4
//   All three convs: split-bf16 (hi+lo) MFMA 32x32x16, NHWC padded-16x16 A.
//   Then 1x1 heads -> scores(8,1614) -> greedy-NMS top6 -> bilinear crop.
// R5 (consolidation): R0 conv1 verbatim (fastest of 5 variants, 41.5us) +
//     R4 small-tile conv2/3 (1 iter, high block count) + unified prep +
//     float4 reduces + SEPARATE heads(51 blk)/nms(8 blk, LDS-only) +
//     new float4 crop (4 px/thread, shared row y-interp). 10 dispatches.
// Output floats: part_imgs[7225344], coords[192], top_prob[48], top_idx[48]
// ---------------------------------------------------------------------------

#define OFF_COORDS 7225344
#define OFF_PROB   7225536
#define OFF_IDX    7225584
#define NA 1614
#define K1TOT 18432

typedef __attribute__((ext_vector_type(8)))  short  short8;
typedef __attribute__((ext_vector_type(16))) float  floatx16;

__device__ inline void split_bf16(float v, unsigned short& h, unsigned short& l)
{
    __hip_bfloat16 hb = __float2bfloat16(v);
    float hv = __bfloat162float(hb);
    __hip_bfloat16 lb = __float2bfloat16(v - hv);
    h = *reinterpret_cast<unsigned short*>(&hb);
    l = *reinterpret_cast<unsigned short*>(&lb);
}

// ---- unified prep: 3200 blocks ---------------------------------------------
//  [0,1024)      prep_a : rpn NCHW fp32 -> padded NHWC split-bf16
//  [1024,2048)   prep_b1: wd1 -> b1 [co][tap*2048+ci] split-bf16 (LDS transpose)
//  [2048,3200)   prep_w23: wd2/wd3 -> b2/b3 [co][tap*128+ci]
__global__ __launch_bounds__(256) void k_prep(const float* __restrict__ rpn,
                                              const float* __restrict__ w1,
                                              const float* __restrict__ w2,
                                              const float* __restrict__ w3,
                                              unsigned short* __restrict__ ah,
                                              unsigned short* __restrict__ al,
                                              unsigned short* __restrict__ b1h,
                                              unsigned short* __restrict__ b1l,
                                              unsigned short* __restrict__ b2h,
                                              unsigned short* __restrict__ b2l,
                                              unsigned short* __restrict__ b3h,
                                              unsigned short* __restrict__ b3l)
{
    __shared__ float tileA[64][65];
    __shared__ float tileB[9][260];
    const int bid = blockIdx.x;
    const int t   = threadIdx.x;

    if (bid < 1024) {                     // ---- prep_a
        const int cib  = (bid & 31) * 64;
        const int posb = ((bid >> 5) & 3) * 64;
        const int b    = bid >> 7;
#pragma unroll
        for (int it = 0; it < 16; ++it) {
            int idx  = it * 256 + t;
            int cil  = idx >> 6;
            int posl = idx & 63;
            int pos  = posb + posl;
            int py = pos >> 4, px = pos & 15;
            int y = py - 1, x = px - 1;
            float v = 0.0f;
            if ((unsigned)y < 14u && (unsigned)x < 14u)
                v = rpn[((size_t)(b * 2048 + cib + cil) * 14 + y) * 14 + x];
            tileA[cil][posl] = v;
        }
        __syncthreads();
#pragma unroll
        for (int it = 0; it < 16; ++it) {
            int idx  = it * 256 + t;
            int posl = idx >> 6;
            int cil  = idx & 63;
            float v = tileA[cil][posl];
            unsigned short h, l;
            split_bf16(v, h, l);
            size_t o = (size_t)(b * 256 + posb + posl) * 2048 + cib + cil;
            ah[o] = h; al[o] = l;
        }
    } else if (bid < 2048) {              // ---- prep_b (conv1)
        const int lb  = bid - 1024;
        const int ci0 = (lb & 7) * 256;
        const int co  = lb >> 3;
        const float* wc = w1 + (size_t)co * K1TOT + (size_t)ci0 * 9;
#pragma unroll
        for (int it = 0; it < 9; ++it) {
            int i = it * 256 + t;
            float v = wc[i];
            tileB[i % 9][i / 9] = v;
        }
        __syncthreads();
#pragma unroll
        for (int tap = 0; tap < 9; ++tap) {
            float v = tileB[tap][t];
            unsigned short h, l;
            split_bf16(v, h, l);
            size_t o = (size_t)co * K1TOT + (size_t)tap * 2048 + ci0 + t;
            b1h[o] = h; b1l[o] = l;
        }
    } else {                              // ---- prep_w23
        const int lb  = bid - 2048;
        const int tap = lb % 9;
        const int co  = lb / 9;
        const int z   = t >> 7;
        const int ci  = t & 127;
        const float* w = z ? w3 : w2;
        unsigned short* bh = z ? b3h : b2h;
        unsigned short* bl = z ? b3l : b2l;
        float v = w[((size_t)co * 128 + ci) * 9 + tap];
        unsigned short h, l;
        split_bf16(v, h, l);
        size_t o = (size_t)co * 1152 + tap * 128 + ci;
        bh[o] = h; bl[o] = l;
    }
}

// ---- conv1: R0-verbatim split-bf16 MFMA implicit-GEMM ---------------------
// Block 128m x 128n, 4 waves (2x2 of 64x64), K-stage 32, K-split grid.y.
template<int POSN, int OW, int STR, int CIN, int MTOT>
__global__ __launch_bounds__(256) void k_conv_mfma(const short* __restrict__ ah,
                                                   const short* __restrict__ al,
                                                   const short* __restrict__ bh,
                                                   const short* __restrict__ bl,
                                                   float* __restrict__ partial,
                                                   int chunk)
{
    constexpr int KTOT = CIN * 9;
    __shared__ short AsH[128][40];
    __shared__ short AsL[128][40];
    __shared__ short BsH[128][40];
    __shared__ short BsL[128][40];

    const int t     = threadIdx.x;
    const int lane  = t & 63;
    const int w     = t >> 6;
    const int wm    = (w & 1) * 64;
    const int wn    = (w >> 1) * 64;
    const int lm    = lane & 31;
    const int half  = lane >> 5;
    const int mbase = blockIdx.x * 128;
    const int k0    = blockIdx.y * chunk;
    const int k1    = (k0 + chunk < KTOT) ? (k0 + chunk) : KTOT;

    int arow[2], apos[2]; bool aval[2];
    const int akc = (t & 3) * 8;
#pragma unroll
    for (int i = 0; i < 2; ++i) {
        int row = ((i * 256 + t) >> 2);
        int m   = mbase + row;
        arow[i] = row;
        aval[i] = (m < MTOT);
        int mm = aval[i] ? m : 0;
        int b  = mm / POSN;
        int p  = mm - b * POSN;
        int y  = p / OW;
        int x  = p - y * OW;
        apos[i] = b * 256 + y * STR * 16 + x * STR;
    }

    floatx16 acc[2][2];
#pragma unroll
    for (int mf = 0; mf < 2; ++mf)
#pragma unroll
        for (int nf = 0; nf < 2; ++nf)
#pragma unroll
            for (int r = 0; r < 16; ++r) acc[mf][nf][r] = 0.0f;

    const short8 zero8 = {0, 0, 0, 0, 0, 0, 0, 0};

    for (int ks = k0; ks < k1; ks += 32) {
        const int tap = ks / CIN;        // stage (32) never straddles a tap
        const int ci0 = ks - tap * CIN;
        const int dy  = tap / 3, dx = tap - dy * 3;
#pragma unroll
        for (int i = 0; i < 2; ++i) {
            short8 vh = zero8, vl = zero8;
            if (aval[i]) {
                size_t g = (size_t)(apos[i] + dy * 16 + dx) * CIN + ci0 + akc;
                vh = *(const short8*)(ah + g);
                vl = *(const short8*)(al + g);
            }
            *(short8*)&AsH[arow[i]][akc] = vh;
            *(short8*)&AsL[arow[i]][akc] = vl;
        }
#pragma unroll
        for (int i = 0; i < 2; ++i) {
            int n = ((i * 256 + t) >> 2);
            size_t g = (size_t)n * KTOT + ks + akc;
            *(short8*)&BsH[n][akc] = *(const short8*)(bh + g);
            *(short8*)&BsL[n][akc] = *(const short8*)(bl + g);
        }
        __syncthreads();
#pragma unroll
        for (int kst = 0; kst < 2; ++kst) {
            const int koff = kst * 16 + half * 8;
            short8 a_h[2], a_l[2], b_h[2], b_l[2];
#pragma unroll
            for (int mf = 0; mf < 2; ++mf) {
                a_h[mf] = *(const short8*)&AsH[wm + mf * 32 + lm][koff];
                a_l[mf] = *(const short8*)&AsL[wm + mf * 32 + lm][koff];
            }
#pragma unroll
            for (int nf = 0; nf < 2; ++nf) {
                b_h[nf] = *(const short8*)&BsH[wn + nf * 32 + lm][koff];
                b_l[nf] = *(const short8*)&BsL[wn + nf * 32 + lm][koff];
            }
#pragma unroll
            for (int mf = 0; mf < 2; ++mf)
#pragma unroll
                for (int nf = 0; nf < 2; ++nf) {
                    acc[mf][nf] = __builtin_amdgcn_mfma_f32_32x32x16_bf16(
                        a_h[mf], b_h[nf], acc[mf][nf], 0, 0, 0);
                    acc[mf][nf] = __builtin_amdgcn_mfma_f32_32x32x16_bf16(
                        a_h[mf], b_l[nf], acc[mf][nf], 0, 0, 0);
                    acc[mf][nf] = __builtin_amdgcn_mfma_f32_32x32x16_bf16(
                        a_l[mf], b_h[nf], acc[mf][nf], 0, 0, 0);
                }
        }
        __syncthreads();
    }

    float* P = partial + (size_t)blockIdx.y * MTOT * 128;
#pragma unroll
    for (int mf = 0; mf < 2; ++mf)
#pragma unroll
        for (int nf = 0; nf < 2; ++nf)
#pragma unroll
            for (int r = 0; r < 16; ++r) {
                int row = (r & 3) + 8 * (r >> 2) + 4 * half;
                int m = mbase + wm + mf * 32 + row;
                int n = wn + nf * 32 + lm;
                if (m < MTOT) P[(size_t)m * 128 + n] = acc[mf][nf][r];
            }
}

// ---- conv2/3: 64-row m-tile, 2 waves, 128 threads (R4, 1 iter/block) ------
template<int POSN, int OW, int STR, int CIN, int MTOT>
__global__ __launch_bounds__(128) void k_conv64(const short* __restrict__ ah,
                                                const short* __restrict__ al,
                                                const short* __restrict__ bh,
                                                const short* __restrict__ bl,
                                                float* __restrict__ partial,
                                                int chunk)
{
    constexpr int KTOT = CIN * 9;
    __shared__ short AsH[64][40];
    __shared__ short AsL[64][40];
    __shared__ short BsH[128][40];
    __shared__ short BsL[128][40];

    const int t     = threadIdx.x;
    const int lane  = t & 63;
    const int w     = t >> 6;            // 0..1
    const int wn    = w * 64;
    const int lm    = lane & 31;
    const int half  = lane >> 5;
    const int mbase = blockIdx.x * 64;
    const int kc    = blockIdx.y;
    const int k0    = kc * chunk;
    const int k1    = (k0 + chunk < KTOT) ? (k0 + chunk) : KTOT;

    const int akc = (t & 3) * 8;
    int arow[2], apos[2]; bool aval[2];
#pragma unroll
    for (int i = 0; i < 2; ++i) {
        int slot = i * 128 + t;
        int row  = slot >> 2;            // 0..63
        int m    = mbase + row;
        arow[i] = row;
        aval[i] = (m < MTOT);
        int mm = aval[i] ? m : 0;
        int b  = mm / POSN;
        int p  = mm - b * POSN;
        int y  = p / OW;
        int x  = p - y * OW;
        apos[i] = b * 256 + y * STR * 16 + x * STR;
    }

    floatx16 acc[2][2];
#pragma unroll
    for (int mf = 0; mf < 2; ++mf)
#pragma unroll
        for (int nf = 0; nf < 2; ++nf)
#pragma unroll
            for (int r = 0; r < 16; ++r) acc[mf][nf][r] = 0.0f;

    const short8 zero8 = {0, 0, 0, 0, 0, 0, 0, 0};

    for (int ks = k0; ks < k1; ks += 32) {
        const int tap = ks / CIN;
        const int ci0 = ks - tap * CIN;
        const int dy  = tap / 3, dx = tap - dy * 3;
#pragma unroll
        for (int i = 0; i < 2; ++i) {
            short8 vh = zero8, vl = zero8;
            if (aval[i]) {
                size_t g = (size_t)(apos[i] + dy * 16 + dx) * CIN + ci0 + akc;
                vh = *(const short8*)(ah + g);
                vl = *(const short8*)(al + g);
            }
            *(short8*)&AsH[arow[i]][akc] = vh;
            *(short8*)&AsL[arow[i]][akc] = vl;
        }
#pragma unroll
        for (int j = 0; j < 4; ++j) {
            int n = ((j * 128 + t) >> 2);    // 0..127
            size_t g = (size_t)n * KTOT + ks + akc;
            *(short8*)&BsH[n][akc] = *(const short8*)(bh + g);
            *(short8*)&BsL[n][akc] = *(const short8*)(bl + g);
        }
        __syncthreads();
#pragma unroll
        for (int kst = 0; kst < 2; ++kst) {
            const int koff = kst * 16 + half * 8;
            short8 a_h[2], a_l[2], b_h[2], b_l[2];
#pragma unroll
            for (int mf = 0; mf < 2; ++mf) {
                a_h[mf] = *(const short8*)&AsH[mf * 32 + lm][koff];
                a_l[mf] = *(const short8*)&AsL[mf * 32 + lm][koff];
            }
#pragma unroll
            for (int nf = 0; nf < 2; ++nf) {
                b_h[nf] = *(const short8*)&BsH[wn + nf * 32 + lm][koff];
                b_l[nf] = *(const short8*)&BsL[wn + nf * 32 + lm][koff];
            }
#pragma unroll
            for (int mf = 0; mf < 2; ++mf)
#pragma unroll
                for (int nf = 0; nf < 2; ++nf) {
                    acc[mf][nf] = __builtin_amdgcn_mfma_f32_32x32x16_bf16(
                        a_h[mf], b_h[nf], acc[mf][nf], 0, 0, 0);
                    acc[mf][nf] = __builtin_amdgcn_mfma_f32_32x32x16_bf16(
                        a_h[mf], b_l[nf], acc[mf][nf], 0, 0, 0);
                    acc[mf][nf] = __builtin_amdgcn_mfma_f32_32x32x16_bf16(
                        a_l[mf], b_h[nf], acc[mf][nf], 0, 0, 0);
                }
        }
        __syncthreads();
    }

    float* P = partial + (size_t)kc * MTOT * 128;
#pragma unroll
    for (int mf = 0; mf < 2; ++mf)
#pragma unroll
        for (int nf = 0; nf < 2; ++nf)
#pragma unroll
            for (int r = 0; r < 16; ++r) {
                int row = (r & 3) + 8 * (r >> 2) + 4 * half;
                int m = mbase + mf * 32 + row;
                int n = wn + nf * 32 + lm;
                if (m < MTOT) P[(size_t)m * 128 + n] = acc[mf][nf][r];
            }
}

// ---- fused reduce: partials + bias + relu -> NHWC fp32 + padded bf16 hi/lo
template<int POSN, int OWV>
__global__ __launch_bounds__(256) void k_reduce_pad(const float* __restrict__ partial,
                                                    const float* __restrict__ bias,
                                                    float* __restrict__ dn,
                                                    __hip_bfloat16* __restrict__ ph,
                                                    __hip_bfloat16* __restrict__ pl,
                                                    int S)
{
    constexpr int MTOT = 8 * POSN;
    int idx = blockIdx.x * 256 + threadIdx.x;   // < 8*256*32
    int b   = idx >> 13;
    int pos = (idx >> 5) & 255;
    int c4  = idx & 31;
    int y = (pos >> 4) - 1;
    int x = (pos & 15) - 1;
    if ((unsigned)y < (unsigned)OWV && (unsigned)x < (unsigned)OWV) {
        int m = b * POSN + y * OWV + x;
        float4 s = ((const float4*)bias)[c4];
        for (int k = 0; k < S; ++k) {
            float4 p = ((const float4*)(partial + (size_t)k * MTOT * 128 + (size_t)m * 128))[c4];
            s.x += p.x; s.y += p.y; s.z += p.z; s.w += p.w;
        }
        s.x = fmaxf(s.x, 0.0f); s.y = fmaxf(s.y, 0.0f);
        s.z = fmaxf(s.z, 0.0f); s.w = fmaxf(s.w, 0.0f);
        ((float4*)dn)[(size_t)m * 32 + c4] = s;
        ushort4 h, l;
        split_bf16(s.x, h.x, l.x);
        split_bf16(s.y, h.y, l.y);
        split_bf16(s.z, h.z, l.z);
        split_bf16(s.w, h.w, l.w);
        ((ushort4*)ph)[idx] = h;
        ((ushort4*)pl)[idx] = l;
    } else {
        ushort4 z = {0, 0, 0, 0};
        ((ushort4*)ph)[idx] = z;
        ((ushort4*)pl)[idx] = z;
    }
}

// ---- reduce conv3 (no pad output) -> NHWC fp32 [8][16][128], float4 -------
__global__ __launch_bounds__(256) void k_reduce3(const float* __restrict__ partial,
                                                 const float* __restrict__ bias,
                                                 float* __restrict__ dn, int S)
{
    int idx = blockIdx.x * 256 + threadIdx.x;   // < 4096 float4 slots
    int c4  = idx & 31;
    float4 s = ((const float4*)bias)[c4];
    for (int k = 0; k < S; ++k) {
        float4 p = ((const float4*)(partial + (size_t)k * 128 * 128))[idx];
        s.x += p.x; s.y += p.y; s.z += p.z; s.w += p.w;
    }
    s.x = fmaxf(s.x, 0.0f); s.y = fmaxf(s.y, 0.0f);
    s.z = fmaxf(s.z, 0.0f); s.w = fmaxf(s.w, 0.0f);
    ((float4*)dn)[idx] = s;
}

// ---- 1x1 heads on NHWC fp32: contiguous 128-deep dots (51 blocks) ---------
__global__ __launch_bounds__(256) void k_heads(const float* __restrict__ d1n,
                                               const float* __restrict__ d2n,
                                               const float* __restrict__ d3n,
                                               const float* __restrict__ w1, const float* __restrict__ b1,
                                               const float* __restrict__ w2, const float* __restrict__ b2,
                                               const float* __restrict__ w3, const float* __restrict__ b3,
                                               float* __restrict__ scores)
{
    int idx = blockIdx.x * 256 + threadIdx.x;
    if (idx >= 8 * NA) return;
    int b = idx / NA;
    int e = idx - b * NA;
    const float* d; const float* w; float bias;
    if (e < 1176) {
        int c = e / 196, p = e - c * 196;
        d = d1n + (size_t)(b * 196 + p) * 128; w = w1 + c * 128; bias = b1[c];
    } else if (e < 1470) {
        int e2 = e - 1176; int c = e2 / 49, p = e2 - c * 49;
        d = d2n + (size_t)(b * 49 + p) * 128; w = w2 + c * 128; bias = b2[c];
    } else {
        int e2 = e - 1470; int c = e2 / 16, p = e2 - c * 16;
        d = d3n + (size_t)(b * 16 + p) * 128; w = w3 + c * 128; bias = b3[c];
    }
    float s = bias;
#pragma unroll
    for (int i = 0; i < 32; ++i) {
        float4 dv = ((const float4*)d)[i];
        float4 wv = ((const float4*)w)[i];
        s = fmaf(dv.x, wv.x, s);
        s = fmaf(dv.y, wv.y, s);
        s = fmaf(dv.z, wv.z, s);
        s = fmaf(dv.w, wv.w, s);
    }
    scores[idx] = s;
}

// ---- NMS + top-6 (greedy NMS truncated at 6 == 6x argmax+suppress) --------
__global__ __launch_bounds__(256) void k_nms_topk(const float* __restrict__ scores,
                                                  const float* __restrict__ anchors,
                                                  float* __restrict__ out,
                                                  int* __restrict__ boxes)
{
    __shared__ float ms[NA];
    __shared__ float ay0[NA], ax0[NA], ay1[NA], ax1[NA];
    __shared__ unsigned char picked[NA];
    __shared__ float rv[4]; __shared__ int ri[4];
    __shared__ float win[5];
    int b = blockIdx.x;
    int t = threadIdx.x;
    for (int i = t; i < NA; i += 256) {
        ms[i] = scores[b * NA + i];
        float4 an = ((const float4*)anchors)[i];
        ay0[i] = an.x; ax0[i] = an.y; ay1[i] = an.z; ax1[i] = an.w;
        picked[i] = 0;
    }
    __syncthreads();
    for (int r = 0; r < 6; ++r) {
        float bv = -INFINITY; int bi = NA;
        for (int i = t; i < NA; i += 256) {
            if (!picked[i]) {
                float v = ms[i];
                if (v > bv || (v == bv && i < bi)) { bv = v; bi = i; }
            }
        }
#pragma unroll
        for (int off = 32; off > 0; off >>= 1) {
            float v2 = __shfl_down(bv, off);
            int   i2 = __shfl_down(bi, off);
            if (v2 > bv || (v2 == bv && i2 < bi)) { bv = v2; bi = i2; }
        }
        if ((t & 63) == 0) { rv[t >> 6] = bv; ri[t >> 6] = bi; }
        __syncthreads();
        if (t == 0) {
            bv = rv[0]; bi = ri[0];
            for (int wv = 1; wv < 4; ++wv)
                if (rv[wv] > bv || (rv[wv] == bv && ri[wv] < bi)) { bv = rv[wv]; bi = ri[wv]; }
            picked[bi] = 1;
            win[0] = ay0[bi]; win[1] = ax0[bi]; win[2] = ay1[bi]; win[3] = ax1[bi]; win[4] = bv;
            int o = b * 6 + r;
            out[OFF_COORDS + o * 4 + 0] = ax0[bi];
            out[OFF_COORDS + o * 4 + 1] = ay0[bi];
            out[OFF_COORDS + o * 4 + 2] = ax1[bi];
            out[OFF_COORDS + o * 4 + 3] = ay1[bi];
            out[OFF_PROB + o] = bv;
            out[OFF_IDX  + o] = (float)bi;
            boxes[o * 4 + 0] = (int)ax0[bi];
            boxes[o * 4 + 1] = (int)ay0[bi];
            boxes[o * 4 + 2] = (int)ax1[bi];
            boxes[o * 4 + 3] = (int)ay1[bi];
        }
        __syncthreads();
        float by0 = win[0], bx0 = win[1], by1 = win[2], bx1 = win[3];
        float barea = (by1 - by0) * (bx1 - bx0);
        for (int i = t; i < NA; i += 256) {
            if (picked[i]) continue;
            float ih = fmaxf(fminf(by1, ay1[i]) - fmaxf(by0, ay0[i]), 0.0f);
            float iw = fmaxf(fminf(bx1, ax1[i]) - fmaxf(bx0, ax0[i]), 0.0f);
            float inter = ih * iw;
            float area  = (ay1[i] - ay0[i]) * (ax1[i] - ax0[i]);
            float iou = inter / (barea + area - inter);
            if (iou > 0.25f) ms[i] = -INFINITY;
        }
        __syncthreads();
    }
}

// ---- bilinear crop-resize: 4 consecutive x-outputs per thread, float4 store
__global__ __launch_bounds__(256) void k_crop4(const float* __restrict__ x,
                                               const int* __restrict__ boxes,
                                               float* __restrict__ out)
{
    int idx = blockIdx.x * 256 + threadIdx.x;   // < 48*3*224*56
    int qi  = idx % 56;
    int j   = (idx / 56) % 224;
    int rem = idx / (56 * 224);
    int c   = rem % 3;
    int br  = rem / 3;
    int b   = br / 6;
    int4 bx = ((const int4*)boxes)[br];
    // row-shared y interpolation
    float tj = (float)j / 223.0f;
    float sy = (float)bx.y + tj * (float)(bx.w - 1 - bx.y);
    int y0i = (int)floorf(sy);
    int y1i = min(y0i + 1, bx.w - 1);
    float wy = sy - (float)y0i;
    const float* img = x + ((size_t)b * 3 + c) * 448 * 448;
    auto g = [&](int yy, int xx) -> float {
        yy -= 224; xx -= 224;
        if ((unsigned)yy >= 448u || (unsigned)xx >= 448u) return 0.0f;
        return img[(size_t)yy * 448 + xx];
    };
    float4 o;
#pragma unroll
    for (int e = 0; e < 4; ++e) {
        int i = qi * 4 + e;
        float ti = (float)i / 223.0f;
        float sx = (float)bx.x + ti * (float)(bx.z - 1 - bx.x);
        int x0i = (int)floorf(sx);
        int x1i = min(x0i + 1, bx.z - 1);
        float wx = sx - (float)x0i;
        float g00 = g(y0i, x0i), g01 = g(y0i, x1i);
        float g10 = g(y1i, x0i), g11 = g(y1i, x1i);
        float top = (1.0f - wx) * g00 + wx * g01;
        float bot = (1.0f - wx) * g10 + wx * g11;
        float v = (1.0f - wy) * top + wy * bot;
        if (e == 0) o.x = v; else if (e == 1) o.y = v;
        else if (e == 2) o.z = v; else o.w = v;
    }
    ((float4*)out)[idx] = o;
}

// ---------------------------------------------------------------------------
extern "C" void kernel_launch(void* const* d_in, const int* in_sizes, int n_in,
                              void* d_out, int out_size, void* d_ws, size_t ws_size,
                              hipStream_t stream)
{
    (void)in_sizes; (void)n_in; (void)out_size;
    const float* x    = (const float*)d_in[0];
    const float* rpn  = (const float*)d_in[1];
    const float* anch = (const float*)d_in[2];
    const float* wd1  = (const float*)d_in[3];
    const float* bd1  = (const float*)d_in[4];
    const float* wd2  = (const float*)d_in[5];
    const float* bd2  = (const float*)d_in[6];
    const float* wd3  = (const float*)d_in[7];
    const float* bd3  = (const float*)d_in[8];
    const float* hw1  = (const float*)d_in[9];
    const float* hb1  = (const float*)d_in[10];
    const float* hw2  = (const float*)d_in[11];
    const float* hb2  = (const float*)d_in[12];
    const float* hw3  = (const float*)d_in[13];
    const float* hb3  = (const float*)d_in[14];
    float* out = (float*)d_out;

    char* ws = (char*)d_ws;
    size_t off = 0;
    auto alloc = [&](size_t bytes) -> void* {
        void* p = ws + off;
        off = (off + bytes + 255) & ~(size_t)255;
        return p;
    };
    unsigned short* ahb = (unsigned short*)alloc((size_t)8 * 256 * 2048 * 2);
    unsigned short* alb = (unsigned short*)alloc((size_t)8 * 256 * 2048 * 2);
    unsigned short* b1h = (unsigned short*)alloc((size_t)128 * K1TOT * 2);
    unsigned short* b1l = (unsigned short*)alloc((size_t)128 * K1TOT * 2);
    unsigned short* b2h = (unsigned short*)alloc((size_t)128 * 1152 * 2);
    unsigned short* b2l = (unsigned short*)alloc((size_t)128 * 1152 * 2);
    unsigned short* b3h = (unsigned short*)alloc((size_t)128 * 1152 * 2);
    unsigned short* b3l = (unsigned short*)alloc((size_t)128 * 1152 * 2);
    __hip_bfloat16* d1ph = (__hip_bfloat16*)alloc((size_t)8 * 256 * 128 * 2);
    __hip_bfloat16* d1pl = (__hip_bfloat16*)alloc((size_t)8 * 256 * 128 * 2);
    __hip_bfloat16* d2ph = (__hip_bfloat16*)alloc((size_t)8 * 256 * 128 * 2);
    __hip_bfloat16* d2pl = (__hip_bfloat16*)alloc((size_t)8 * 256 * 128 * 2);
    float* d1n  = (float*)alloc((size_t)8 * 196 * 128 * 4);
    float* d2n  = (float*)alloc((size_t)8 * 49 * 128 * 4);
    float* d3n  = (float*)alloc((size_t)8 * 16 * 128 * 4);
    float* sc   = (float*)alloc((size_t)8 * NA * 4);
    int*  boxes = (int*)alloc((size_t)8 * 6 * 4 * 4);
    size_t avail = (ws_size > off) ? (ws_size - off) : 0;
    float* P = (float*)(ws + off);

    long long s1 = (long long)(avail / ((size_t)1568 * 128 * 4));
    if (s1 > 48) s1 = 48;
    if (s1 < 1)  s1 = 1;
    int S1 = (int)s1;
    int chunk1 = ((K1TOT + S1 * 32 - 1) / (S1 * 32)) * 32;

    // 1) unified prep (weights + conv1 input)
    k_prep<<<dim3(3200), 256, 0, stream>>>(rpn, wd1, wd2, wd3,
        ahb, alb, b1h, b1l, b2h, b2l, b3h, b3l);

    // 2) conv1: M=1568, CIN=2048, 128-row tiles (R0 verbatim), grid 13 x S1
    k_conv_mfma<196, 14, 1, 2048, 1568><<<dim3(13, S1), 256, 0, stream>>>(
        (const short*)ahb, (const short*)alb, (const short*)b1h, (const short*)b1l, P, chunk1);
    k_reduce_pad<196, 14><<<dim3(256), 256, 0, stream>>>(P, bd1, d1n, d1ph, d1pl, S1);

    // 3) conv2: M=392, CIN=128, K=1152, 64-row tiles, grid 7 x 36 (1 iter)
    k_conv64<49, 7, 2, 128, 392><<<dim3(7, 36), 128, 0, stream>>>(
        (const short*)d1ph, (const short*)d1pl, (const short*)b2h, (const short*)b2l, P, 32);
    k_reduce_pad<49, 7><<<dim3(256), 256, 0, stream>>>(P, bd2, d2n, d2ph, d2pl, 36);

    // 4) conv3: M=128, CIN=128, K=1152, 64-row tiles, grid 2 x 36 (1 iter)
    k_conv64<16, 4, 2, 128, 128><<<dim3(2, 36), 128, 0, stream>>>(
        (const short*)d2ph, (const short*)d2pl, (const short*)b3h, (const short*)b3l, P, 32);
    k_reduce3<<<dim3(16), 256, 0, stream>>>(P, bd3, d3n, 36);

    // 5) heads (51 blocks) -> scores
    k_heads<<<dim3((8 * NA + 255) / 256), 256, 0, stream>>>(d1n, d2n, d3n,
        hw1, hb1, hw2, hb2, hw3, hb3, sc);

    // 6) NMS + top-6 (LDS-only, 8 blocks)
    k_nms_topk<<<dim3(8), 256, 0, stream>>>(sc, anch, out, boxes);

    // 7) bilinear crop, 4 px/thread, float4 stores
    k_crop4<<<dim3(7056), 256, 0, stream>>>(x, boxes, out);
}